// Round 4
// baseline (533.105 us; speedup 1.0000x reference)
//
#include <hip/hip_runtime.h>
#include <math.h>

#define TPB 256

// ---- analytic Wigner-3j constants (verified R1: absmax 0.0156) ----
#define R10   0.31622776601683794f  // 1/sqrt(10)
#define R30   0.18257418583505536f  // 1/sqrt(30)
#define R30x2 0.36514837167011072f  // 2/sqrt(30)
#define C222_SIGN (1.0f)            // verified R1
#define CCA (C222_SIGN * 0.23904572186687872f) // 2/sqrt(70)
#define CCB (C222_SIGN * 0.20701966780270623f) // sqrt(3/70)
#define CCC (C222_SIGN * 0.11952286093343936f) // 1/sqrt(70)

#define TROW 144   // table row stride (140 used, padded)

typedef float f4 __attribute__((ext_vector_type(4)));

__device__ __forceinline__ void atomAddF(float* p, float v) {
    __hip_atomic_fetch_add(p, v, __ATOMIC_RELAXED, __HIP_MEMORY_SCOPE_AGENT);
}

// 6-step segmented inclusive scan over 36 regs.
// R8: takes array by reference — after inlining all indices are constant GEPs,
// so SROA promotes b[] fully to VGPRs (R3's float* aliases kept it in scratch).
__device__ __forceinline__ void segscan36(float (&b)[36], int dist) {
#pragma unroll
    for (int s = 1; s < 64; s <<= 1) {
        float msk = (dist >= s) ? 1.f : 0.f;
#pragma unroll
        for (int j = 0; j < 36; ++j) {
            float t = __shfl_up(b[j], s);
            b[j] = fmaf(msk, t, b[j]);
        }
    }
}

// Tail-write of 36 accumulated values. No bitcast of b: vectors are BUILT from
// elements (insertelement), only the GLOBAL pointer is cast.
__device__ __forceinline__ void emit36(const float (&b)[36], float* o, bool partial) {
    if (partial) {
#pragma unroll
        for (int j = 0; j < 36; ++j) atomAddF(o + j, b[j]);
    } else {
#pragma unroll
        for (int q = 0; q < 9; ++q) {
            f4 v;
            v[0] = b[4 * q + 0];
            v[1] = b[4 * q + 1];
            v[2] = b[4 * q + 2];
            v[3] = b[4 * q + 3];
            *(f4*)(o + 4 * q) = v;
        }
    }
}

// ============ node records (stride 44) + col histogram into cursor ============
__global__ __launch_bounds__(256) void build_rec_count(const float* __restrict__ f_in,
                                                       const float* __restrict__ pos,
                                                       const int* __restrict__ eidx,
                                                       float* __restrict__ rec,
                                                       int* __restrict__ cnt,
                                                       int N, int E) {
    int i = blockIdx.x * 256 + threadIdx.x;
    if (i < N) {
        const float* f = f_in + (size_t)i * 162;
        float* r = rec + (size_t)i * 44;
        r[0] = pos[i * 3 + 0]; r[1] = pos[i * 3 + 1]; r[2] = pos[i * 3 + 2];
        float2 v0 = *(const float2*)f;
        r[3] = v0.x + v0.y;
#pragma unroll
        for (int u = 0; u < 3; ++u)
#pragma unroll
            for (int v = 0; v < 3; ++v) {
                float2 a = *(const float2*)(f + ((1 + u) * 9 + (1 + v)) * 2);
                r[4 + u * 3 + v] = a.x + a.y;
            }
        r[13] = 0.f; r[14] = 0.f; r[15] = 0.f;
#pragma unroll
        for (int u = 0; u < 5; ++u)
#pragma unroll
            for (int v = 0; v < 5; ++v) {
                float2 a = *(const float2*)(f + ((4 + u) * 9 + (4 + v)) * 2);
                r[16 + u * 5 + v] = a.x + a.y;
            }
        r[41] = 0.f; r[42] = 0.f; r[43] = 0.f;
    }
    if (i < E) atomicAdd(&cnt[eidx[E + i]], 1);
}

// ============ radial FC table: row bin = exact FC outputs at r = bin*Delta ============
// cols 0..11 = S (x12), 12..59 = P (x48), 60..139 = D (x80), pre-scaled by base*kf.
__global__ __launch_bounds__(256) void build_table(const float* __restrict__ W1s,
                                                   const float* __restrict__ W2s,
                                                   const float* __restrict__ W1p,
                                                   const float* __restrict__ W2p,
                                                   const float* __restrict__ W1d,
                                                   const float* __restrict__ W2d,
                                                   float* __restrict__ table,
                                                   float Delta, float base) {
    __shared__ float t3[192];
    const int tid = threadIdx.x;
    const float r = (float)blockIdx.x * Delta;

    // --- 2-nonzero radial basis (R5-verified formula) ---
    const float F = (float)(1.14136 * 7.38905609893065 * 3.1622776601683795);
    float qq = r * 2.2f;
    int a0 = (int)floorf(qq) - 1;
    int ac = min(max(a0, 0), 8);
    float d0 = qq - (float)(ac + 1);
    float d0s = d0 * d0;
    float ea = (d0s < 1.f) ? F * expf(-2.f / (1.f - d0s)) : 0.f;
    float d1 = d0 - 1.f;
    float d1s = d1 * d1;
    float eb = (d1s < 1.f) ? F * expf(-2.f / (1.f - d1s)) : 0.f;

    if (tid < 192) {
        int path = tid >> 6, j = tid & 63;
        const float* W1 = (path == 0) ? W1s : (path == 1) ? W1p : W1d;
        float u = W1[ac * 64 + j];
        float v = W1[(ac + 1) * 64 + j];
        t3[tid] = fmaxf(fmaf(eb, v, ea * u), 0.f);
    }
    __syncthreads();
    if (tid >= 140) return;

    const float* W2; const float* t; int M, m; float kf;
    if (tid < 12) {
        W2 = W2s; t = t3; M = 12; m = tid; kf = 1.f;
    } else if (tid < 60) {
        W2 = W2p; t = t3 + 64; M = 48; m = tid - 12;
        kf = (m < 12) ? 0.40824829046386307f
           : (m < 24) ? 0.33333333333333333f
           : (m < 36) ? 1.29099444873580560f
                      : 0.70710678118654752f;
    } else {
        W2 = W2d; t = t3 + 128; M = 80; m = tid - 60;
        kf = (m < 20) ? 0.31622776601683794f
           : (m < 40) ? 0.77459666924148340f
           : (m < 60) ? 0.2f
                      : 0.70710678118654752f;
    }
    float acc = 0.f;
#pragma unroll 4
    for (int j = 0; j < 64; ++j)
        acc = fmaf(t[j], W2[j * M + m], acc);
    table[(size_t)blockIdx.x * TROW + tid] = acc * (base * kf);
}

// ============ exclusive scan, IN PLACE over `data` (1 block; R5-verified core) ============
// no __restrict__: in-place aliasing is intentional (each thread reads its 4 before writing).
__global__ __launch_bounds__(1024) void scan_kernel(int* data, int N) {
    __shared__ int wsum[16];
    const int tid = threadIdx.x;
    const int lane = tid & 63;
    const int wv = tid >> 6;
    int carry = 0;
    for (int base = 0; base < N; base += 4096) {
        int i0 = base + tid * 4;
        int v0 = (i0 + 0 < N) ? data[i0 + 0] : 0;
        int v1 = (i0 + 1 < N) ? data[i0 + 1] : 0;
        int v2 = (i0 + 2 < N) ? data[i0 + 2] : 0;
        int v3 = (i0 + 3 < N) ? data[i0 + 3] : 0;
        int s = v0 + v1 + v2 + v3;
        int sc = s;
        for (int d = 1; d < 64; d <<= 1) {
            int t = __shfl_up(sc, d);
            if (lane >= d) sc += t;
        }
        if (lane == 63) wsum[wv] = sc;
        __syncthreads();
        int woff = carry, tot = carry;
#pragma unroll
        for (int w = 0; w < 16; ++w) {
            int x = wsum[w];
            if (w < wv) woff += x;
            tot += x;
        }
        int excl = woff + (sc - s);
        if (i0 + 0 < N) data[i0 + 0] = excl;
        excl += v0;
        if (i0 + 1 < N) data[i0 + 1] = excl;
        excl += v1;
        if (i0 + 2 < N) data[i0 + 2] = excl;
        excl += v2;
        if (i0 + 3 < N) data[i0 + 3] = excl;
        carry = tot;
        __syncthreads();
    }
}

// ============ permute edges into sorted-by-col order (R5-verified) ============
__global__ __launch_bounds__(256) void permute_kernel(const int* __restrict__ eidx,
                                                      int* __restrict__ cursor,
                                                      int2* __restrict__ edges, int E) {
    int e = blockIdx.x * 256 + threadIdx.x;
    if (e < E) {
        int c = eidx[E + e];
        int p = atomicAdd(&cursor[c], 1);
        edges[p] = make_int2(eidx[e], c);
    }
}

// ============ fused: table-lerp FC + per-edge TP + wave segmented reduce ============
// R8: SROA-clean local arrays (constant indices only, no float*/float4* aliases of
//     locals, no array-capturing lambdas) so b[36]/xp/xd live in VGPRs, not scratch.
//     waves_per_eu(3,3) keeps the allocator at the 3-wave/EU budget (~170 VGPR).
__global__ __launch_bounds__(TPB)
__attribute__((amdgpu_waves_per_eu(3, 3)))
void fused3_kernel(
    const float* __restrict__ rec,
    const int2*  __restrict__ edges,
    const float* __restrict__ table,
    float* __restrict__ out,
    int E, int NB, float invDelta)
{
    const int tid = threadIdx.x;
    const int lane = tid & 63;

    const int p = blockIdx.x * TPB + tid;
    const bool valid = p < E;
    int2 ed = valid ? edges[p] : make_int2(0, 0x7fffffff);
    const int row = ed.x;
    const int col = ed.y;
    const int colIdx = valid ? col : 0;

    // ---- wave-local segmentation (R5-verified) ----
    int prevCol = __shfl_up(col, 1);
    bool head = (lane == 0) || (col != prevCol);
    unsigned long long m = __ballot(head);
    unsigned long long below = m & ((2ull << lane) - 1ull);
    const int hd = 63 - __builtin_clzll(below);
    const bool tail = (lane == 63) ? true : (((m >> (lane + 1)) & 1ull) != 0);
    const int dist = lane - hd;
    int clf = 0, crf = 0;
    if (lane == 0 && valid && p > 0)        clf = (edges[p - 1].y == col);
    if (lane == 63 && valid && (p + 1) < E) crf = (edges[p + 1].y == col);
    const int contL = __shfl(clf, 0);
    const int contR = __shfl(crf, 63);
    const bool partial = (hd == 0 && contL) || (lane == 63 && contR);
    const bool doWrite = tail && valid;

    // ---- geometry (R5-verified) ----
    const float* rr = rec + (size_t)row * 44;
    const float fm = valid ? 1.f : 0.f;
    float4 h0 = *(const float4*)(rr);
    float4 qc = *(const float4*)(rec + (size_t)colIdx * 44);

    float ex = h0.x - qc.x, ey = h0.y - qc.y, ez = h0.z - qc.z;
    float r = sqrtf(ex * ex + ey * ey + ez * ez + 1e-12f);
    float rinv = 1.0f / r;
    float x = ex * rinv, y = ey * rinv, z = ez * rinv;

    float sh1 = 1.7320508075688772f * x;
    float sh2 = 1.7320508075688772f * y;
    float sh3 = 1.7320508075688772f * z;
    float sh4 = 3.8729833462074170f * x * z;
    float sh5 = 3.8729833462074170f * x * y;
    float sh6 = 1.1180339887498949f * (2.f * y * y - x * x - z * z);
    float sh7 = 3.8729833462074170f * y * z;
    float sh8 = 1.9364916731037085f * (z * z - x * x);

    // ---- radial table lookup: bin + lerp frac (FC==0 exactly for r>=5) ----
    float rn = r * invDelta;
    int bin = (int)floorf(rn);
    float f = rn - (float)bin;
    if (bin >= NB) { bin = NB - 1; f = 1.f; }   // table[NB] == 0 row (exact)
    const float* T0 = table + (size_t)bin * TROW;
    const float* T1 = T0 + TROW;

    // load+lerp 4 contiguous table cols; returns vector BY VALUE (SROA-safe)
    auto lerpv = [&](int off) -> f4 {
        f4 a = *(const f4*)(T0 + off);
        f4 c = *(const f4*)(T1 + off);
        f4 w;
        w[0] = fmaf(f, c[0] - a[0], a[0]);
        w[1] = fmaf(f, c[1] - a[1], a[1]);
        w[2] = fmaf(f, c[2] - a[2], a[2]);
        w[3] = fmaf(f, c[3] - a[3], a[3]);
        return w;
    };

    float b[36];

    // ================= S path (table cols 0..11 -> out 0..35) =================
    {
        f4 wsA = lerpv(0);
        f4 wsB = lerpv(4);
        f4 wsC = lerpv(8);
        float X = h0.w * fm;
#pragma unroll
        for (int w = 0; w < 4; ++w) {
            b[w] = X * wsA[w];
            float t1 = X * wsB[w];
            b[4 + w * 3 + 0] = t1 * sh1;
            b[4 + w * 3 + 1] = t1 * sh2;
            b[4 + w * 3 + 2] = t1 * sh3;
            float t2 = X * wsC[w];
            b[16 + w * 5 + 0] = t2 * sh4;
            b[16 + w * 5 + 1] = t2 * sh5;
            b[16 + w * 5 + 2] = t2 * sh6;
            b[16 + w * 5 + 3] = t2 * sh7;
            b[16 + w * 5 + 4] = t2 * sh8;
        }
        segscan36(b, dist);
        if (doWrite) emit36(b, out + (size_t)col * 108 + 0, partial);
    }

    // ================= P path (table cols 12..59 -> out 36..71) =================
    {
        // coalesced vector loads from GLOBAL rec, element-copied into a
        // constant-indexed plain array (SROA promotes xp fully)
        f4 xv0 = *(const f4*)(rr + 4);
        f4 xv1 = *(const f4*)(rr + 8);
        float xp[9];
        xp[0] = xv0[0]; xp[1] = xv0[1]; xp[2] = xv0[2]; xp[3] = xv0[3];
        xp[4] = xv1[0]; xp[5] = xv1[1]; xp[6] = xv1[2]; xp[7] = xv1[3];
        xp[8] = rr[12];
#pragma unroll
        for (int t = 0; t < 36; ++t) b[t] = 0.f;
#pragma unroll
        for (int u = 0; u < 3; ++u) {
            // stream this u's 16 weights: kinds at cols 12/24/36/48 + u*4
            f4 wa = lerpv(12 + u * 4);
            f4 wb = lerpv(24 + u * 4);
            f4 wc = lerpv(36 + u * 4);
            f4 wd2 = lerpv(48 + u * 4);
            float x0 = xp[u * 3 + 0] * fm, x1 = xp[u * 3 + 1] * fm, x2 = xp[u * 3 + 2] * fm;
            float dot = x0 * sh1 + x1 * sh2 + x2 * sh3;
            float ya0 = R10 * (x0 * sh3 + x2 * sh1);
            float ya1 = R10 * (x0 * sh2 + x1 * sh1);
            float ya2 = R30 * (2.f * x1 * sh2 - x0 * sh1 - x2 * sh3);
            float ya3 = R10 * (x1 * sh3 + x2 * sh2);
            float ya4 = R10 * (x2 * sh3 - x0 * sh1);
            float yb0 = R10 * (x2 * sh4 + x1 * sh5 - x0 * sh8) - R30 * x0 * sh6;
            float yb1 = R10 * (x0 * sh5 + x2 * sh7) + R30x2 * x1 * sh6;
            float yb2 = R10 * (x0 * sh4 + x1 * sh7 + x2 * sh8) - R30 * x2 * sh6;
#pragma unroll
            for (int w = 0; w < 4; ++w) {
                b[w] = fmaf(dot, wb[w], b[w]);
                b[4 + w * 3 + 0] = fmaf(x0, wa[w], fmaf(yb0, wd2[w], b[4 + w * 3 + 0]));
                b[4 + w * 3 + 1] = fmaf(x1, wa[w], fmaf(yb1, wd2[w], b[4 + w * 3 + 1]));
                b[4 + w * 3 + 2] = fmaf(x2, wa[w], fmaf(yb2, wd2[w], b[4 + w * 3 + 2]));
                b[16 + w * 5 + 0] = fmaf(ya0, wc[w], b[16 + w * 5 + 0]);
                b[16 + w * 5 + 1] = fmaf(ya1, wc[w], b[16 + w * 5 + 1]);
                b[16 + w * 5 + 2] = fmaf(ya2, wc[w], b[16 + w * 5 + 2]);
                b[16 + w * 5 + 3] = fmaf(ya3, wc[w], b[16 + w * 5 + 3]);
                b[16 + w * 5 + 4] = fmaf(ya4, wc[w], b[16 + w * 5 + 4]);
            }
        }
        segscan36(b, dist);
        if (doWrite) emit36(b, out + (size_t)col * 108 + 36, partial);
    }

    // ================= D path (table cols 60..139 -> out 72..107) =================
    {
        f4 dv0 = *(const f4*)(rr + 16);
        f4 dv1 = *(const f4*)(rr + 20);
        f4 dv2 = *(const f4*)(rr + 24);
        f4 dv3 = *(const f4*)(rr + 28);
        f4 dv4 = *(const f4*)(rr + 32);
        f4 dv5 = *(const f4*)(rr + 36);
        float xd[25];
        xd[0]  = dv0[0]; xd[1]  = dv0[1]; xd[2]  = dv0[2]; xd[3]  = dv0[3];
        xd[4]  = dv1[0]; xd[5]  = dv1[1]; xd[6]  = dv1[2]; xd[7]  = dv1[3];
        xd[8]  = dv2[0]; xd[9]  = dv2[1]; xd[10] = dv2[2]; xd[11] = dv2[3];
        xd[12] = dv3[0]; xd[13] = dv3[1]; xd[14] = dv3[2]; xd[15] = dv3[3];
        xd[16] = dv4[0]; xd[17] = dv4[1]; xd[18] = dv4[2]; xd[19] = dv4[3];
        xd[20] = dv5[0]; xd[21] = dv5[1]; xd[22] = dv5[2]; xd[23] = dv5[3];
        xd[24] = rr[40];
#pragma unroll
        for (int t = 0; t < 36; ++t) b[t] = 0.f;
#pragma unroll
        for (int u = 0; u < 5; ++u) {
            // stream this u's 16 weights: kinds at cols 60/80/100/120 + u*4
            f4 wa = lerpv(60  + u * 4);
            f4 wb = lerpv(80  + u * 4);
            f4 wc = lerpv(100 + u * 4);
            f4 we = lerpv(120 + u * 4);
            float x0 = xd[u * 5 + 0] * fm, x1 = xd[u * 5 + 1] * fm, x2 = xd[u * 5 + 2] * fm;
            float x3 = xd[u * 5 + 3] * fm, x4 = xd[u * 5 + 4] * fm;
            float dot = x0 * sh4 + x1 * sh5 + x2 * sh6 + x3 * sh7 + x4 * sh8;
            float yb0 = R10 * (x0 * sh3 + x1 * sh2 - x4 * sh1) - R30 * x2 * sh1;
            float yb1 = R10 * (x1 * sh1 + x3 * sh3) + R30x2 * x2 * sh2;
            float yb2 = R10 * (x0 * sh1 + x3 * sh2 + x4 * sh3) - R30 * x2 * sh3;
            float yc0 = CCA * (x2 * sh4 + x0 * sh6) - CCB * (x1 * sh7 + x3 * sh5);
            float yc1 = CCB * (x1 * sh8 + x4 * sh5 - x0 * sh7 - x3 * sh4)
                      - CCC * (x1 * sh6 + x2 * sh5);
            float yc2 = CCA * (x0 * sh4 - x2 * sh6 + x4 * sh8)
                      - CCC * (x1 * sh5 + x3 * sh7);
            float yc3 = -CCB * (x0 * sh5 + x1 * sh4 + x3 * sh8 + x4 * sh7)
                      - CCC * (x2 * sh7 + x3 * sh6);
            float yc4 = CCB * (x1 * sh5 - x3 * sh7) + CCA * (x2 * sh8 + x4 * sh6);
#pragma unroll
            for (int w = 0; w < 4; ++w) {
                b[w] = fmaf(dot, wc[w], b[w]);
                b[4 + w * 3 + 0] = fmaf(yb0, wb[w], b[4 + w * 3 + 0]);
                b[4 + w * 3 + 1] = fmaf(yb1, wb[w], b[4 + w * 3 + 1]);
                b[4 + w * 3 + 2] = fmaf(yb2, wb[w], b[4 + w * 3 + 2]);
                b[16 + w * 5 + 0] = fmaf(x0, wa[w], fmaf(yc0, we[w], b[16 + w * 5 + 0]));
                b[16 + w * 5 + 1] = fmaf(x1, wa[w], fmaf(yc1, we[w], b[16 + w * 5 + 1]));
                b[16 + w * 5 + 2] = fmaf(x2, wa[w], fmaf(yc2, we[w], b[16 + w * 5 + 2]));
                b[16 + w * 5 + 3] = fmaf(x3, wa[w], fmaf(yc3, we[w], b[16 + w * 5 + 3]));
                b[16 + w * 5 + 4] = fmaf(x4, wa[w], fmaf(yc4, we[w], b[16 + w * 5 + 4]));
            }
        }
        segscan36(b, dist);
        if (doWrite) emit36(b, out + (size_t)col * 108 + 72, partial);
    }
}

// ============ fallback: R1 atomic kernel (verified; no workspace needed) ============
template<int M>
__device__ __forceinline__ void fc_eval(const float* sW1T, const float* sW2,
                                        const float emb[12], float* acc)
{
#pragma unroll
    for (int m = 0; m < M; ++m) acc[m] = 0.f;
#pragma unroll 2
    for (int j = 0; j < 64; ++j) {
        const float4* w1r = (const float4*)(sW1T + j * 12);
        float4 A = w1r[0], B = w1r[1], C = w1r[2];
        float t = A.x*emb[0] + A.y*emb[1] + A.z*emb[2] + A.w*emb[3]
                + B.x*emb[4] + B.y*emb[5] + B.z*emb[6] + B.w*emb[7]
                + C.x*emb[8] + C.y*emb[9];
        t = fmaxf(t, 0.f);
        const float4* w2r = (const float4*)(sW2 + j * M);
#pragma unroll
        for (int q = 0; q < M / 4; ++q) {
            float4 V = w2r[q];
            acc[4*q+0] = fmaf(t, V.x, acc[4*q+0]);
            acc[4*q+1] = fmaf(t, V.y, acc[4*q+1]);
            acc[4*q+2] = fmaf(t, V.z, acc[4*q+2]);
            acc[4*q+3] = fmaf(t, V.w, acc[4*q+3]);
        }
    }
}

__global__ __launch_bounds__(TPB) void eqconv_edge_kernel_atomic(
    const float* __restrict__ f_in,
    const int*   __restrict__ eidx,
    const float* __restrict__ pos,
    const float* __restrict__ W1s_g, const float* __restrict__ W2s_g,
    const float* __restrict__ W1p_g, const float* __restrict__ W2p_g,
    const float* __restrict__ W1d_g, const float* __restrict__ W2d_g,
    float* __restrict__ out,
    int E, float snorm)
{
    __shared__ __align__(16) float smem[11264];
    float* tW1s = smem;
    float* tW1p = smem + 768;
    float* tW1d = smem + 1536;
    float* sW2s = smem + 2304;
    float* sW2p = smem + 3072;
    float* sW2d = smem + 6144;

    const int tid = threadIdx.x;
    const float base = 0.05590169943749474f * snorm;

    for (int idx = tid; idx < 768; idx += TPB) {
        int j = idx / 12, i = idx - j * 12;
        tW1s[idx] = (i < 10) ? W1s_g[i * 64 + j] : 0.f;
        tW1p[idx] = (i < 10) ? W1p_g[i * 64 + j] : 0.f;
        tW1d[idx] = (i < 10) ? W1d_g[i * 64 + j] : 0.f;
    }
    for (int idx = tid; idx < 768; idx += TPB)
        sW2s[idx] = W2s_g[idx] * base;
    for (int idx = tid; idx < 3072; idx += TPB) {
        int m = idx % 48;
        float k = (m < 12) ? 0.40824829046386307f
                : (m < 24) ? 0.33333333333333333f
                : (m < 36) ? 1.29099444873580560f
                           : 0.70710678118654752f;
        sW2p[idx] = W2p_g[idx] * (base * k);
    }
    for (int idx = tid; idx < 5120; idx += TPB) {
        int m = idx % 80;
        float k = (m < 20) ? 0.31622776601683794f
                : (m < 40) ? 0.77459666924148340f
                : (m < 60) ? 0.2f
                           : 0.70710678118654752f;
        sW2d[idx] = W2d_g[idx] * (base * k);
    }
    __syncthreads();

    int e = blockIdx.x * TPB + tid;
    if (e >= E) return;

    const int row = eidx[e];
    const int col = eidx[E + e];

    float ex = pos[row * 3 + 0] - pos[col * 3 + 0];
    float ey = pos[row * 3 + 1] - pos[col * 3 + 1];
    float ez = pos[row * 3 + 2] - pos[col * 3 + 2];
    float r = sqrtf(ex * ex + ey * ey + ez * ez + 1e-12f);
    float rinv = 1.0f / r;
    float x = ex * rinv, y = ey * rinv, z = ez * rinv;

    float sh1 = 1.7320508075688772f * x;
    float sh2 = 1.7320508075688772f * y;
    float sh3 = 1.7320508075688772f * z;
    float sh4 = 3.8729833462074170f * x * z;
    float sh5 = 3.8729833462074170f * x * y;
    float sh6 = 1.1180339887498949f * (2.f * y * y - x * x - z * z);
    float sh7 = 3.8729833462074170f * y * z;
    float sh8 = 1.9364916731037085f * (z * z - x * x);

    float emb[12];
    {
        const float F = (float)(1.14136 * 7.38905609893065 * 3.1622776601683795);
        const float inv_step = 2.2f;
#pragma unroll
        for (int i = 0; i < 10; ++i) {
            float v = (float)(i + 1) * (5.0f / 11.0f);
            float d = (r - v) * inv_step;
            float d2 = d * d;
            emb[i] = (d2 < 1.0f) ? F * expf(-2.0f / (1.0f - d2)) : 0.f;
        }
        emb[10] = 0.f; emb[11] = 0.f;
    }

    const float* fr = f_in + (size_t)row * 162;
    float* o = out + (size_t)col * 108;

    {
        float ws[12];
        fc_eval<12>(tW1s, sW2s, emb, ws);
        float2 v0 = *(const float2*)(fr);
        float X = v0.x + v0.y;
#pragma unroll
        for (int w = 0; w < 4; ++w) {
            atomAddF(o + w, X * ws[w]);
            float t1 = X * ws[4 + w];
            atomAddF(o + 4 + w * 3 + 0, t1 * sh1);
            atomAddF(o + 4 + w * 3 + 1, t1 * sh2);
            atomAddF(o + 4 + w * 3 + 2, t1 * sh3);
            float t2 = X * ws[8 + w];
            atomAddF(o + 16 + w * 5 + 0, t2 * sh4);
            atomAddF(o + 16 + w * 5 + 1, t2 * sh5);
            atomAddF(o + 16 + w * 5 + 2, t2 * sh6);
            atomAddF(o + 16 + w * 5 + 3, t2 * sh7);
            atomAddF(o + 16 + w * 5 + 4, t2 * sh8);
        }
    }
    {
        float wp[48];
        fc_eval<48>(tW1p, sW2p, emb, wp);
        float op0[4] = {0.f,0.f,0.f,0.f};
        float op1[12], op2[20];
#pragma unroll
        for (int t = 0; t < 12; ++t) op1[t] = 0.f;
#pragma unroll
        for (int t = 0; t < 20; ++t) op2[t] = 0.f;
#pragma unroll
        for (int u = 0; u < 3; ++u) {
            float2 a0 = *(const float2*)(fr + ((1 + u) * 9 + 1) * 2);
            float2 a1 = *(const float2*)(fr + ((1 + u) * 9 + 2) * 2);
            float2 a2 = *(const float2*)(fr + ((1 + u) * 9 + 3) * 2);
            float x0 = a0.x + a0.y, x1 = a1.x + a1.y, x2 = a2.x + a2.y;
            float dot = x0 * sh1 + x1 * sh2 + x2 * sh3;
            float ya0 = R10 * (x0 * sh3 + x2 * sh1);
            float ya1 = R10 * (x0 * sh2 + x1 * sh1);
            float ya2 = R30 * (2.f * x1 * sh2 - x0 * sh1 - x2 * sh3);
            float ya3 = R10 * (x1 * sh3 + x2 * sh2);
            float ya4 = R10 * (x2 * sh3 - x0 * sh1);
            float yb0 = R10 * (x2 * sh4 + x1 * sh5 - x0 * sh8) - R30 * x0 * sh6;
            float yb1 = R10 * (x0 * sh5 + x2 * sh7) + R30x2 * x1 * sh6;
            float yb2 = R10 * (x0 * sh4 + x1 * sh7 + x2 * sh8) - R30 * x2 * sh6;
#pragma unroll
            for (int w = 0; w < 4; ++w) {
                float wa = wp[u * 4 + w];
                float wb = wp[12 + u * 4 + w];
                float wc = wp[24 + u * 4 + w];
                float wd2 = wp[36 + u * 4 + w];
                op0[w] = fmaf(dot, wb, op0[w]);
                op1[w * 3 + 0] = fmaf(x0, wa, fmaf(yb0, wd2, op1[w * 3 + 0]));
                op1[w * 3 + 1] = fmaf(x1, wa, fmaf(yb1, wd2, op1[w * 3 + 1]));
                op1[w * 3 + 2] = fmaf(x2, wa, fmaf(yb2, wd2, op1[w * 3 + 2]));
                op2[w * 5 + 0] = fmaf(ya0, wc, op2[w * 5 + 0]);
                op2[w * 5 + 1] = fmaf(ya1, wc, op2[w * 5 + 1]);
                op2[w * 5 + 2] = fmaf(ya2, wc, op2[w * 5 + 2]);
                op2[w * 5 + 3] = fmaf(ya3, wc, op2[w * 5 + 3]);
                op2[w * 5 + 4] = fmaf(ya4, wc, op2[w * 5 + 4]);
            }
        }
#pragma unroll
        for (int w = 0; w < 4; ++w) atomAddF(o + 36 + w, op0[w]);
#pragma unroll
        for (int t = 0; t < 12; ++t) atomAddF(o + 40 + t, op1[t]);
#pragma unroll
        for (int t = 0; t < 20; ++t) atomAddF(o + 52 + t, op2[t]);
    }
    {
        float wd[80];
        fc_eval<80>(tW1d, sW2d, emb, wd);
        float od0[4] = {0.f,0.f,0.f,0.f};
        float od1[12], od2[20];
#pragma unroll
        for (int t = 0; t < 12; ++t) od1[t] = 0.f;
#pragma unroll
        for (int t = 0; t < 20; ++t) od2[t] = 0.f;
#pragma unroll
        for (int u = 0; u < 5; ++u) {
            float2 b0 = *(const float2*)(fr + ((4 + u) * 9 + 4) * 2);
            float2 b1 = *(const float2*)(fr + ((4 + u) * 9 + 5) * 2);
            float2 b2 = *(const float2*)(fr + ((4 + u) * 9 + 6) * 2);
            float2 b3 = *(const float2*)(fr + ((4 + u) * 9 + 7) * 2);
            float2 b4 = *(const float2*)(fr + ((4 + u) * 9 + 8) * 2);
            float x0 = b0.x + b0.y, x1 = b1.x + b1.y, x2 = b2.x + b2.y;
            float x3 = b3.x + b3.y, x4 = b4.x + b4.y;
            float dot = x0 * sh4 + x1 * sh5 + x2 * sh6 + x3 * sh7 + x4 * sh8;
            float yb0 = R10 * (x0 * sh3 + x1 * sh2 - x4 * sh1) - R30 * x2 * sh1;
            float yb1 = R10 * (x1 * sh1 + x3 * sh3) + R30x2 * x2 * sh2;
            float yb2 = R10 * (x0 * sh1 + x3 * sh2 + x4 * sh3) - R30 * x2 * sh3;
            float yc0 = CCA * (x2 * sh4 + x0 * sh6) - CCB * (x1 * sh7 + x3 * sh5);
            float yc1 = CCB * (x1 * sh8 + x4 * sh5 - x0 * sh7 - x3 * sh4)
                      - CCC * (x1 * sh6 + x2 * sh5);
            float yc2 = CCA * (x0 * sh4 - x2 * sh6 + x4 * sh8)
                      - CCC * (x1 * sh5 + x3 * sh7);
            float yc3 = -CCB * (x0 * sh5 + x1 * sh4 + x3 * sh8 + x4 * sh7)
                      - CCC * (x2 * sh7 + x3 * sh6);
            float yc4 = CCB * (x1 * sh5 - x3 * sh7) + CCA * (x2 * sh8 + x4 * sh6);
#pragma unroll
            for (int w = 0; w < 4; ++w) {
                float wa = wd[u * 4 + w];
                float wb = wd[20 + u * 4 + w];
                float wc = wd[40 + u * 4 + w];
                float we = wd[60 + u * 4 + w];
                od0[w] = fmaf(dot, wc, od0[w]);
                od1[w * 3 + 0] = fmaf(yb0, wb, od1[w * 3 + 0]);
                od1[w * 3 + 1] = fmaf(yb1, wb, od1[w * 3 + 1]);
                od1[w * 3 + 2] = fmaf(yb2, wb, od1[w * 3 + 2]);
                od2[w * 5 + 0] = fmaf(x0, wa, fmaf(yc0, we, od2[w * 5 + 0]));
                od2[w * 5 + 1] = fmaf(x1, wa, fmaf(yc1, we, od2[w * 5 + 1]));
                od2[w * 5 + 2] = fmaf(x2, wa, fmaf(yc2, we, od2[w * 5 + 2]));
                od2[w * 5 + 3] = fmaf(x3, wa, fmaf(yc3, we, od2[w * 5 + 3]));
                od2[w * 5 + 4] = fmaf(x4, wa, fmaf(yc4, we, od2[w * 5 + 4]));
            }
        }
#pragma unroll
        for (int w = 0; w < 4; ++w) atomAddF(o + 72 + w, od0[w]);
#pragma unroll
        for (int t = 0; t < 12; ++t) atomAddF(o + 76 + t, od1[t]);
#pragma unroll
        for (int t = 0; t < 20; ++t) atomAddF(o + 88 + t, od2[t]);
    }
}

extern "C" void kernel_launch(void* const* d_in, const int* in_sizes, int n_in,
                              void* d_out, int out_size, void* d_ws, size_t ws_size,
                              hipStream_t stream) {
    const float* f_in = (const float*)d_in[0];
    const int*   eidx = (const int*)d_in[1];
    const float* pos  = (const float*)d_in[2];
    const float* W1s = (const float*)d_in[5];
    const float* W2s = (const float*)d_in[6];
    const float* W1p = (const float*)d_in[7];
    const float* W2p = (const float*)d_in[8];
    const float* W1d = (const float*)d_in[9];
    const float* W2d = (const float*)d_in[10];

    const int E = in_sizes[1] / 2;
    const int N = in_sizes[0] / 162;
    const float snorm = (float)(1.0 / sqrt((double)E / (double)N));
    const float base = 0.05590169943749474f * snorm;   // sqrt2/(8*sqrt10) * snorm
    const int eBlocks = (E + 255) / 256;
    const int numTiles = (E + TPB - 1) / TPB;

    // ws: edges int2[E] | cursor[N] (histogram+in-place scan) | rec[44N] | table[(NB+1)*TROW]
    const size_t edgesBytes = (size_t)E * sizeof(int2);
    const size_t curOff  = edgesBytes;
    const size_t recOff  = (curOff + (size_t)N * sizeof(int) + 15) & ~((size_t)15);
    const size_t tabOff  = (recOff + (size_t)N * 44 * sizeof(float) + 15) & ~((size_t)15);

    // dynamic table size: prefer 2048 bins, degrade if workspace is tight
    int NB = 0;
    if (ws_size > tabOff) {
        size_t rows = (ws_size - tabOff) / (TROW * sizeof(float));
        if (rows >= 513) NB = (int)((rows - 1) < 2048 ? (rows - 1) : 2048);
    }

    if (NB >= 512) {
        int2*  edges  = (int2*)d_ws;
        int*   cursor = (int*)((char*)d_ws + curOff);
        float* rec    = (float*)((char*)d_ws + recOff);
        float* table  = (float*)((char*)d_ws + tabOff);
        const float Delta = 5.0f / (float)NB;
        const float invDelta = (float)NB / 5.0f;

        hipMemsetAsync(cursor, 0, (size_t)N * sizeof(int), stream);
        hipMemsetAsync(d_out, 0, (size_t)out_size * sizeof(float), stream);
        build_rec_count<<<eBlocks, 256, 0, stream>>>(f_in, pos, eidx, rec, cursor, N, E);
        build_table<<<NB + 1, 256, 0, stream>>>(W1s, W2s, W1p, W2p, W1d, W2d,
                                                table, Delta, base);
        scan_kernel<<<1, 1024, 0, stream>>>(cursor, N);
        permute_kernel<<<eBlocks, 256, 0, stream>>>(eidx, cursor, edges, E);
        fused3_kernel<<<numTiles, TPB, 0, stream>>>(
            rec, edges, table, (float*)d_out, E, NB, invDelta);
    } else {
        hipMemsetAsync(d_out, 0, (size_t)out_size * sizeof(float), stream);
        eqconv_edge_kernel_atomic<<<eBlocks, TPB, 0, stream>>>(
            f_in, eidx, pos, W1s, W2s, W1p, W2p, W1d, W2d,
            (float*)d_out, E, snorm);
    }
}

// Round 5
// 390.047 us; speedup vs baseline: 1.3668x; 1.3668x over previous
//
#include <hip/hip_runtime.h>
#include <math.h>

#define TPB 256

// ---- analytic Wigner-3j constants (verified R1: absmax 0.0156) ----
#define R10   0.31622776601683794f  // 1/sqrt(10)
#define R30   0.18257418583505536f  // 1/sqrt(30)
#define R30x2 0.36514837167011072f  // 2/sqrt(30)
#define CCA (0.23904572186687872f)  // 2/sqrt(70)
#define CCB (0.20701966780270623f)  // sqrt(3/70)
#define CCC (0.11952286093343936f)  // 1/sqrt(70)

#define TROW 144   // table row stride (floats)
#define RSTR 56    // rec row stride (floats): pos(3),Xs(1),P(9)@4..12,pad,D 5x[f4+1+pad]@16+u*8

typedef float f4 __attribute__((ext_vector_type(4)));

__device__ __forceinline__ void atomAddF(float* p, float v) {
    __hip_atomic_fetch_add(p, v, __ATOMIC_RELAXED, __HIP_MEMORY_SCOPE_AGENT);
}

// ============ node records (stride 56) + col histogram into cursor ============
__global__ __launch_bounds__(256) void build_rec_count(const float* __restrict__ f_in,
                                                       const float* __restrict__ pos,
                                                       const int* __restrict__ eidx,
                                                       float* __restrict__ rec,
                                                       int* __restrict__ cnt,
                                                       int N, int E) {
    int i = blockIdx.x * 256 + threadIdx.x;
    if (i < N) {
        const float* f = f_in + (size_t)i * 162;
        float* r = rec + (size_t)i * RSTR;
        r[0] = pos[i * 3 + 0]; r[1] = pos[i * 3 + 1]; r[2] = pos[i * 3 + 2];
        float2 v0 = *(const float2*)f;
        r[3] = v0.x + v0.y;
#pragma unroll
        for (int u = 0; u < 3; ++u)
#pragma unroll
            for (int v = 0; v < 3; ++v) {
                float2 a = *(const float2*)(f + ((1 + u) * 9 + (1 + v)) * 2);
                r[4 + u * 3 + v] = a.x + a.y;
            }
#pragma unroll
        for (int u = 0; u < 5; ++u)
#pragma unroll
            for (int v = 0; v < 5; ++v) {
                float2 a = *(const float2*)(f + ((4 + u) * 9 + (4 + v)) * 2);
                r[16 + u * 8 + v] = a.x + a.y;   // 16B-aligned f4 + scalar per u
            }
    }
    if (i < E) atomicAdd(&cnt[eidx[E + i]], 1);
}

// ============ radial FC table, gather-friendly layout ============
// S: col = w*4 + kind            (kind 0..2; col w*4+3 unused)
// P: col = 16 + w*12 + u*4 + kind  (kind: wa,wb,wc,wd)
// D: col = 64 + w*20 + u*4 + kind  (kind: wa,wb,wc,we)
// so each (w,u) weight fetch in the gather is ONE aligned f4.
__global__ __launch_bounds__(256) void build_table(const float* __restrict__ W1s,
                                                   const float* __restrict__ W2s,
                                                   const float* __restrict__ W1p,
                                                   const float* __restrict__ W2p,
                                                   const float* __restrict__ W1d,
                                                   const float* __restrict__ W2d,
                                                   float* __restrict__ table,
                                                   float Delta, float base) {
    __shared__ float t3[192];
    const int tid = threadIdx.x;
    const float r = (float)blockIdx.x * Delta;

    // --- 2-nonzero radial basis (R5-verified formula) ---
    const float F = (float)(1.14136 * 7.38905609893065 * 3.1622776601683795);
    float qq = r * 2.2f;
    int a0 = (int)floorf(qq) - 1;
    int ac = min(max(a0, 0), 8);
    float d0 = qq - (float)(ac + 1);
    float d0s = d0 * d0;
    float ea = (d0s < 1.f) ? F * expf(-2.f / (1.f - d0s)) : 0.f;
    float d1 = d0 - 1.f;
    float d1s = d1 * d1;
    float eb = (d1s < 1.f) ? F * expf(-2.f / (1.f - d1s)) : 0.f;

    if (tid < 192) {
        int path = tid >> 6, j = tid & 63;
        const float* W1 = (path == 0) ? W1s : (path == 1) ? W1p : W1d;
        float u = W1[ac * 64 + j];
        float v = W1[(ac + 1) * 64 + j];
        t3[tid] = fmaxf(fmaf(eb, v, ea * u), 0.f);
    }
    __syncthreads();
    if (tid >= 140) return;

    const float* W2; const float* t; int M, m; float kf; int newcol;
    if (tid < 12) {
        W2 = W2s; t = t3; M = 12; m = tid; kf = 1.f;
        int kind = m >> 2, w = m & 3;
        newcol = w * 4 + kind;
    } else if (tid < 60) {
        W2 = W2p; t = t3 + 64; M = 48; m = tid - 12;
        kf = (m < 12) ? 0.40824829046386307f
           : (m < 24) ? 0.33333333333333333f
           : (m < 36) ? 1.29099444873580560f
                      : 0.70710678118654752f;
        int kind = m / 12, u = (m % 12) >> 2, w = m & 3;
        newcol = 16 + w * 12 + u * 4 + kind;
    } else {
        W2 = W2d; t = t3 + 128; M = 80; m = tid - 60;
        kf = (m < 20) ? 0.31622776601683794f
           : (m < 40) ? 0.77459666924148340f
           : (m < 60) ? 0.2f
                      : 0.70710678118654752f;
        int kind = m / 20, u = (m % 20) >> 2, w = m & 3;
        newcol = 64 + w * 20 + u * 4 + kind;
    }
    float acc = 0.f;
#pragma unroll 4
    for (int j = 0; j < 64; ++j)
        acc = fmaf(t[j], W2[j * M + m], acc);
    table[(size_t)blockIdx.x * TROW + newcol] = acc * (base * kf);
}

// ============ exclusive scan, IN PLACE over `data` (1 block; R5-verified core) ============
__global__ __launch_bounds__(1024) void scan_kernel(int* data, int N) {
    __shared__ int wsum[16];
    const int tid = threadIdx.x;
    const int lane = tid & 63;
    const int wv = tid >> 6;
    int carry = 0;
    for (int base = 0; base < N; base += 4096) {
        int i0 = base + tid * 4;
        int v0 = (i0 + 0 < N) ? data[i0 + 0] : 0;
        int v1 = (i0 + 1 < N) ? data[i0 + 1] : 0;
        int v2 = (i0 + 2 < N) ? data[i0 + 2] : 0;
        int v3 = (i0 + 3 < N) ? data[i0 + 3] : 0;
        int s = v0 + v1 + v2 + v3;
        int sc = s;
        for (int d = 1; d < 64; d <<= 1) {
            int t = __shfl_up(sc, d);
            if (lane >= d) sc += t;
        }
        if (lane == 63) wsum[wv] = sc;
        __syncthreads();
        int woff = carry, tot = carry;
#pragma unroll
        for (int w = 0; w < 16; ++w) {
            int x = wsum[w];
            if (w < wv) woff += x;
            tot += x;
        }
        int excl = woff + (sc - s);
        if (i0 + 0 < N) data[i0 + 0] = excl;
        excl += v0;
        if (i0 + 1 < N) data[i0 + 1] = excl;
        excl += v1;
        if (i0 + 2 < N) data[i0 + 2] = excl;
        excl += v2;
        if (i0 + 3 < N) data[i0 + 3] = excl;
        carry = tot;
        __syncthreads();
    }
}

// ============ scatter rows into col-sorted order (CSR values) ============
// after this, cursor[c] = END offset of col c (start = cursor[c-1]).
__global__ __launch_bounds__(256) void permute_rows(const int* __restrict__ eidx,
                                                    int* __restrict__ cursor,
                                                    int* __restrict__ rows, int E) {
    int e = blockIdx.x * 256 + threadIdx.x;
    if (e < E) {
        int c = eidx[E + e];
        int p = atomicAdd(&cursor[c], 1);
        rows[p] = eidx[e];
    }
}

// ============ node-centric gather: one (node, path, w) per thread ============
// 9 scalar accumulators per thread; no segscan, no atomics, no output memset.
// Role is block-uniform: blocks [0,bD) = D, [bD,bD+bP) = P, rest = S (D first —
// longest role starts earliest). Per-edge math verbatim from the verified
// fused kernel; only the summation order differs (serial per node).
__global__ __launch_bounds__(256) void gather_kernel(
    const float* __restrict__ rec,
    const int* __restrict__ rows,
    const int* __restrict__ cursor,
    const float* __restrict__ table,
    float* __restrict__ out,
    int N, int NB, float invDelta)
{
    const int bRole = (4 * N + 255) >> 8;       // blocks per role
    int bid = blockIdx.x;
    int role = (bid < bRole) ? 2 : (bid < 2 * bRole) ? 1 : 0;  // 2=D,1=P,0=S
    int lbid = bid - ((role == 2) ? 0 : (role == 1) ? bRole : 2 * bRole);
    int idx = lbid * 256 + threadIdx.x;
    if (idx >= 4 * N) return;
    const int node = idx >> 2;
    const int w = idx & 3;

    const float* rq = rec + (size_t)node * RSTR;
    const float qx = rq[0], qy = rq[1], qz = rq[2];
    const int e0 = (node == 0) ? 0 : cursor[node - 1];
    const int e1 = cursor[node];

    float a0 = 0.f, a1 = 0.f, a2 = 0.f, a3 = 0.f, a4 = 0.f,
          a5 = 0.f, a6 = 0.f, a7 = 0.f, a8 = 0.f;

    for (int p = e0; p < e1; ++p) {
        int row = rows[p];
        const float* rr = rec + (size_t)row * RSTR;
        f4 h0 = *(const f4*)rr;
        float ex = h0[0] - qx, ey = h0[1] - qy, ez = h0[2] - qz;
        float r = sqrtf(ex * ex + ey * ey + ez * ez + 1e-12f);
        float rinv = 1.0f / r;
        float x = ex * rinv, y = ey * rinv, z = ez * rinv;

        float sh1 = 1.7320508075688772f * x;
        float sh2 = 1.7320508075688772f * y;
        float sh3 = 1.7320508075688772f * z;
        float sh4 = 3.8729833462074170f * x * z;
        float sh5 = 3.8729833462074170f * x * y;
        float sh6 = 1.1180339887498949f * (2.f * y * y - x * x - z * z);
        float sh7 = 3.8729833462074170f * y * z;
        float sh8 = 1.9364916731037085f * (z * z - x * x);

        float rn = r * invDelta;
        int bin = (int)floorf(rn);
        float f = rn - (float)bin;
        if (bin >= NB) { bin = NB - 1; f = 1.f; }
        const float* T0 = table + (size_t)bin * TROW;
        const float* T1 = T0 + TROW;

        if (role == 0) {
            // ---- S ----
            f4 ta = *(const f4*)(T0 + w * 4);
            f4 tc = *(const f4*)(T1 + w * 4);
            float ws0 = fmaf(f, tc[0] - ta[0], ta[0]);
            float ws1 = fmaf(f, tc[1] - ta[1], ta[1]);
            float ws2 = fmaf(f, tc[2] - ta[2], ta[2]);
            float X = h0[3];
            a0 = fmaf(X, ws0, a0);
            float t1 = X * ws1;
            a1 = fmaf(t1, sh1, a1);
            a2 = fmaf(t1, sh2, a2);
            a3 = fmaf(t1, sh3, a3);
            float t2 = X * ws2;
            a4 = fmaf(t2, sh4, a4);
            a5 = fmaf(t2, sh5, a5);
            a6 = fmaf(t2, sh6, a6);
            a7 = fmaf(t2, sh7, a7);
            a8 = fmaf(t2, sh8, a8);
        } else if (role == 1) {
            // ---- P ----
            f4 xv0 = *(const f4*)(rr + 4);
            f4 xv1 = *(const f4*)(rr + 8);
            float xp8 = rr[12];
            const float* tp0 = T0 + 16 + w * 12;
            const float* tp1 = T1 + 16 + w * 12;
#pragma unroll
            for (int u = 0; u < 3; ++u) {
                float x0 = (u == 0) ? xv0[0] : (u == 1) ? xv0[3] : xv1[2];
                float x1 = (u == 0) ? xv0[1] : (u == 1) ? xv1[0] : xv1[3];
                float x2 = (u == 0) ? xv0[2] : (u == 1) ? xv1[1] : xp8;
                f4 ta = *(const f4*)(tp0 + u * 4);
                f4 tc = *(const f4*)(tp1 + u * 4);
                f4 wv;
                wv[0] = fmaf(f, tc[0] - ta[0], ta[0]);
                wv[1] = fmaf(f, tc[1] - ta[1], ta[1]);
                wv[2] = fmaf(f, tc[2] - ta[2], ta[2]);
                wv[3] = fmaf(f, tc[3] - ta[3], ta[3]);
                float dot = x0 * sh1 + x1 * sh2 + x2 * sh3;
                float ya0 = R10 * (x0 * sh3 + x2 * sh1);
                float ya1 = R10 * (x0 * sh2 + x1 * sh1);
                float ya2 = R30 * (2.f * x1 * sh2 - x0 * sh1 - x2 * sh3);
                float ya3 = R10 * (x1 * sh3 + x2 * sh2);
                float ya4 = R10 * (x2 * sh3 - x0 * sh1);
                float yb0 = R10 * (x2 * sh4 + x1 * sh5 - x0 * sh8) - R30 * x0 * sh6;
                float yb1 = R10 * (x0 * sh5 + x2 * sh7) + R30x2 * x1 * sh6;
                float yb2 = R10 * (x0 * sh4 + x1 * sh7 + x2 * sh8) - R30 * x2 * sh6;
                a0 = fmaf(dot, wv[1], a0);
                a1 = fmaf(x0, wv[0], fmaf(yb0, wv[3], a1));
                a2 = fmaf(x1, wv[0], fmaf(yb1, wv[3], a2));
                a3 = fmaf(x2, wv[0], fmaf(yb2, wv[3], a3));
                a4 = fmaf(ya0, wv[2], a4);
                a5 = fmaf(ya1, wv[2], a5);
                a6 = fmaf(ya2, wv[2], a6);
                a7 = fmaf(ya3, wv[2], a7);
                a8 = fmaf(ya4, wv[2], a8);
            }
        } else {
            // ---- D ----
            const float* td0 = T0 + 64 + w * 20;
            const float* td1 = T1 + 64 + w * 20;
#pragma unroll
            for (int u = 0; u < 5; ++u) {
                f4 xv = *(const f4*)(rr + 16 + u * 8);
                float x4 = rr[16 + u * 8 + 4];
                float x0 = xv[0], x1 = xv[1], x2 = xv[2], x3 = xv[3];
                f4 ta = *(const f4*)(td0 + u * 4);
                f4 tc = *(const f4*)(td1 + u * 4);
                f4 wv;
                wv[0] = fmaf(f, tc[0] - ta[0], ta[0]);
                wv[1] = fmaf(f, tc[1] - ta[1], ta[1]);
                wv[2] = fmaf(f, tc[2] - ta[2], ta[2]);
                wv[3] = fmaf(f, tc[3] - ta[3], ta[3]);
                float dot = x0 * sh4 + x1 * sh5 + x2 * sh6 + x3 * sh7 + x4 * sh8;
                float yb0 = R10 * (x0 * sh3 + x1 * sh2 - x4 * sh1) - R30 * x2 * sh1;
                float yb1 = R10 * (x1 * sh1 + x3 * sh3) + R30x2 * x2 * sh2;
                float yb2 = R10 * (x0 * sh1 + x3 * sh2 + x4 * sh3) - R30 * x2 * sh3;
                float yc0 = CCA * (x2 * sh4 + x0 * sh6) - CCB * (x1 * sh7 + x3 * sh5);
                float yc1 = CCB * (x1 * sh8 + x4 * sh5 - x0 * sh7 - x3 * sh4)
                          - CCC * (x1 * sh6 + x2 * sh5);
                float yc2 = CCA * (x0 * sh4 - x2 * sh6 + x4 * sh8)
                          - CCC * (x1 * sh5 + x3 * sh7);
                float yc3 = -CCB * (x0 * sh5 + x1 * sh4 + x3 * sh8 + x4 * sh7)
                          - CCC * (x2 * sh7 + x3 * sh6);
                float yc4 = CCB * (x1 * sh5 - x3 * sh7) + CCA * (x2 * sh8 + x4 * sh6);
                a0 = fmaf(dot, wv[2], a0);
                a1 = fmaf(yb0, wv[1], a1);
                a2 = fmaf(yb1, wv[1], a2);
                a3 = fmaf(yb2, wv[1], a3);
                a4 = fmaf(x0, wv[0], fmaf(yc0, wv[3], a4));
                a5 = fmaf(x1, wv[0], fmaf(yc1, wv[3], a5));
                a6 = fmaf(x2, wv[0], fmaf(yc2, wv[3], a6));
                a7 = fmaf(x3, wv[0], fmaf(yc3, wv[3], a7));
                a8 = fmaf(x4, wv[0], fmaf(yc4, wv[3], a8));
            }
        }
    }

    const int obase = (role == 0) ? 0 : (role == 1) ? 36 : 72;
    float* o = out + (size_t)node * 108 + obase;
    o[w] = a0;
    o[4 + w * 3 + 0] = a1;
    o[4 + w * 3 + 1] = a2;
    o[4 + w * 3 + 2] = a3;
    o[16 + w * 5 + 0] = a4;
    o[16 + w * 5 + 1] = a5;
    o[16 + w * 5 + 2] = a6;
    o[16 + w * 5 + 3] = a7;
    o[16 + w * 5 + 4] = a8;
}

// ============ fallback: R1 atomic kernel (verified; no workspace needed) ============
template<int M>
__device__ __forceinline__ void fc_eval(const float* sW1T, const float* sW2,
                                        const float emb[12], float* acc)
{
#pragma unroll
    for (int m = 0; m < M; ++m) acc[m] = 0.f;
#pragma unroll 2
    for (int j = 0; j < 64; ++j) {
        const float4* w1r = (const float4*)(sW1T + j * 12);
        float4 A = w1r[0], B = w1r[1], C = w1r[2];
        float t = A.x*emb[0] + A.y*emb[1] + A.z*emb[2] + A.w*emb[3]
                + B.x*emb[4] + B.y*emb[5] + B.z*emb[6] + B.w*emb[7]
                + C.x*emb[8] + C.y*emb[9];
        t = fmaxf(t, 0.f);
        const float4* w2r = (const float4*)(sW2 + j * M);
#pragma unroll
        for (int q = 0; q < M / 4; ++q) {
            float4 V = w2r[q];
            acc[4*q+0] = fmaf(t, V.x, acc[4*q+0]);
            acc[4*q+1] = fmaf(t, V.y, acc[4*q+1]);
            acc[4*q+2] = fmaf(t, V.z, acc[4*q+2]);
            acc[4*q+3] = fmaf(t, V.w, acc[4*q+3]);
        }
    }
}

__global__ __launch_bounds__(TPB) void eqconv_edge_kernel_atomic(
    const float* __restrict__ f_in,
    const int*   __restrict__ eidx,
    const float* __restrict__ pos,
    const float* __restrict__ W1s_g, const float* __restrict__ W2s_g,
    const float* __restrict__ W1p_g, const float* __restrict__ W2p_g,
    const float* __restrict__ W1d_g, const float* __restrict__ W2d_g,
    float* __restrict__ out,
    int E, float snorm)
{
    __shared__ __align__(16) float smem[11264];
    float* tW1s = smem;
    float* tW1p = smem + 768;
    float* tW1d = smem + 1536;
    float* sW2s = smem + 2304;
    float* sW2p = smem + 3072;
    float* sW2d = smem + 6144;

    const int tid = threadIdx.x;
    const float base = 0.05590169943749474f * snorm;

    for (int idx = tid; idx < 768; idx += TPB) {
        int j = idx / 12, i = idx - j * 12;
        tW1s[idx] = (i < 10) ? W1s_g[i * 64 + j] : 0.f;
        tW1p[idx] = (i < 10) ? W1p_g[i * 64 + j] : 0.f;
        tW1d[idx] = (i < 10) ? W1d_g[i * 64 + j] : 0.f;
    }
    for (int idx = tid; idx < 768; idx += TPB)
        sW2s[idx] = W2s_g[idx] * base;
    for (int idx = tid; idx < 3072; idx += TPB) {
        int m = idx % 48;
        float k = (m < 12) ? 0.40824829046386307f
                : (m < 24) ? 0.33333333333333333f
                : (m < 36) ? 1.29099444873580560f
                           : 0.70710678118654752f;
        sW2p[idx] = W2p_g[idx] * (base * k);
    }
    for (int idx = tid; idx < 5120; idx += TPB) {
        int m = idx % 80;
        float k = (m < 20) ? 0.31622776601683794f
                : (m < 40) ? 0.77459666924148340f
                : (m < 60) ? 0.2f
                           : 0.70710678118654752f;
        sW2d[idx] = W2d_g[idx] * (base * k);
    }
    __syncthreads();

    int e = blockIdx.x * TPB + tid;
    if (e >= E) return;

    const int row = eidx[e];
    const int col = eidx[E + e];

    float ex = pos[row * 3 + 0] - pos[col * 3 + 0];
    float ey = pos[row * 3 + 1] - pos[col * 3 + 1];
    float ez = pos[row * 3 + 2] - pos[col * 3 + 2];
    float r = sqrtf(ex * ex + ey * ey + ez * ez + 1e-12f);
    float rinv = 1.0f / r;
    float x = ex * rinv, y = ey * rinv, z = ez * rinv;

    float sh1 = 1.7320508075688772f * x;
    float sh2 = 1.7320508075688772f * y;
    float sh3 = 1.7320508075688772f * z;
    float sh4 = 3.8729833462074170f * x * z;
    float sh5 = 3.8729833462074170f * x * y;
    float sh6 = 1.1180339887498949f * (2.f * y * y - x * x - z * z);
    float sh7 = 3.8729833462074170f * y * z;
    float sh8 = 1.9364916731037085f * (z * z - x * x);

    float emb[12];
    {
        const float F = (float)(1.14136 * 7.38905609893065 * 3.1622776601683795);
        const float inv_step = 2.2f;
#pragma unroll
        for (int i = 0; i < 10; ++i) {
            float v = (float)(i + 1) * (5.0f / 11.0f);
            float d = (r - v) * inv_step;
            float d2 = d * d;
            emb[i] = (d2 < 1.0f) ? F * expf(-2.0f / (1.0f - d2)) : 0.f;
        }
        emb[10] = 0.f; emb[11] = 0.f;
    }

    const float* fr = f_in + (size_t)row * 162;
    float* o = out + (size_t)col * 108;

    {
        float ws[12];
        fc_eval<12>(tW1s, sW2s, emb, ws);
        float2 v0 = *(const float2*)(fr);
        float X = v0.x + v0.y;
#pragma unroll
        for (int w = 0; w < 4; ++w) {
            atomAddF(o + w, X * ws[w]);
            float t1 = X * ws[4 + w];
            atomAddF(o + 4 + w * 3 + 0, t1 * sh1);
            atomAddF(o + 4 + w * 3 + 1, t1 * sh2);
            atomAddF(o + 4 + w * 3 + 2, t1 * sh3);
            float t2 = X * ws[8 + w];
            atomAddF(o + 16 + w * 5 + 0, t2 * sh4);
            atomAddF(o + 16 + w * 5 + 1, t2 * sh5);
            atomAddF(o + 16 + w * 5 + 2, t2 * sh6);
            atomAddF(o + 16 + w * 5 + 3, t2 * sh7);
            atomAddF(o + 16 + w * 5 + 4, t2 * sh8);
        }
    }
    {
        float wp[48];
        fc_eval<48>(tW1p, sW2p, emb, wp);
        float op0[4] = {0.f,0.f,0.f,0.f};
        float op1[12], op2[20];
#pragma unroll
        for (int t = 0; t < 12; ++t) op1[t] = 0.f;
#pragma unroll
        for (int t = 0; t < 20; ++t) op2[t] = 0.f;
#pragma unroll
        for (int u = 0; u < 3; ++u) {
            float2 a0 = *(const float2*)(fr + ((1 + u) * 9 + 1) * 2);
            float2 a1 = *(const float2*)(fr + ((1 + u) * 9 + 2) * 2);
            float2 a2 = *(const float2*)(fr + ((1 + u) * 9 + 3) * 2);
            float x0 = a0.x + a0.y, x1 = a1.x + a1.y, x2 = a2.x + a2.y;
            float dot = x0 * sh1 + x1 * sh2 + x2 * sh3;
            float ya0 = R10 * (x0 * sh3 + x2 * sh1);
            float ya1 = R10 * (x0 * sh2 + x1 * sh1);
            float ya2 = R30 * (2.f * x1 * sh2 - x0 * sh1 - x2 * sh3);
            float ya3 = R10 * (x1 * sh3 + x2 * sh2);
            float ya4 = R10 * (x2 * sh3 - x0 * sh1);
            float yb0 = R10 * (x2 * sh4 + x1 * sh5 - x0 * sh8) - R30 * x0 * sh6;
            float yb1 = R10 * (x0 * sh5 + x2 * sh7) + R30x2 * x1 * sh6;
            float yb2 = R10 * (x0 * sh4 + x1 * sh7 + x2 * sh8) - R30 * x2 * sh6;
#pragma unroll
            for (int w = 0; w < 4; ++w) {
                float wa = wp[u * 4 + w];
                float wb = wp[12 + u * 4 + w];
                float wc = wp[24 + u * 4 + w];
                float wd2 = wp[36 + u * 4 + w];
                op0[w] = fmaf(dot, wb, op0[w]);
                op1[w * 3 + 0] = fmaf(x0, wa, fmaf(yb0, wd2, op1[w * 3 + 0]));
                op1[w * 3 + 1] = fmaf(x1, wa, fmaf(yb1, wd2, op1[w * 3 + 1]));
                op1[w * 3 + 2] = fmaf(x2, wa, fmaf(yb2, wd2, op1[w * 3 + 2]));
                op2[w * 5 + 0] = fmaf(ya0, wc, op2[w * 5 + 0]);
                op2[w * 5 + 1] = fmaf(ya1, wc, op2[w * 5 + 1]);
                op2[w * 5 + 2] = fmaf(ya2, wc, op2[w * 5 + 2]);
                op2[w * 5 + 3] = fmaf(ya3, wc, op2[w * 5 + 3]);
                op2[w * 5 + 4] = fmaf(ya4, wc, op2[w * 5 + 4]);
            }
        }
#pragma unroll
        for (int w = 0; w < 4; ++w) atomAddF(o + 36 + w, op0[w]);
#pragma unroll
        for (int t = 0; t < 12; ++t) atomAddF(o + 40 + t, op1[t]);
#pragma unroll
        for (int t = 0; t < 20; ++t) atomAddF(o + 52 + t, op2[t]);
    }
    {
        float wd[80];
        fc_eval<80>(tW1d, sW2d, emb, wd);
        float od0[4] = {0.f,0.f,0.f,0.f};
        float od1[12], od2[20];
#pragma unroll
        for (int t = 0; t < 12; ++t) od1[t] = 0.f;
#pragma unroll
        for (int t = 0; t < 20; ++t) od2[t] = 0.f;
#pragma unroll
        for (int u = 0; u < 5; ++u) {
            float2 b0 = *(const float2*)(fr + ((4 + u) * 9 + 4) * 2);
            float2 b1 = *(const float2*)(fr + ((4 + u) * 9 + 5) * 2);
            float2 b2 = *(const float2*)(fr + ((4 + u) * 9 + 6) * 2);
            float2 b3 = *(const float2*)(fr + ((4 + u) * 9 + 7) * 2);
            float2 b4 = *(const float2*)(fr + ((4 + u) * 9 + 8) * 2);
            float x0 = b0.x + b0.y, x1 = b1.x + b1.y, x2 = b2.x + b2.y;
            float x3 = b3.x + b3.y, x4 = b4.x + b4.y;
            float dot = x0 * sh4 + x1 * sh5 + x2 * sh6 + x3 * sh7 + x4 * sh8;
            float yb0 = R10 * (x0 * sh3 + x1 * sh2 - x4 * sh1) - R30 * x2 * sh1;
            float yb1 = R10 * (x1 * sh1 + x3 * sh3) + R30x2 * x2 * sh2;
            float yb2 = R10 * (x0 * sh1 + x3 * sh2 + x4 * sh3) - R30 * x2 * sh3;
            float yc0 = CCA * (x2 * sh4 + x0 * sh6) - CCB * (x1 * sh7 + x3 * sh5);
            float yc1 = CCB * (x1 * sh8 + x4 * sh5 - x0 * sh7 - x3 * sh4)
                      - CCC * (x1 * sh6 + x2 * sh5);
            float yc2 = CCA * (x0 * sh4 - x2 * sh6 + x4 * sh8)
                      - CCC * (x1 * sh5 + x3 * sh7);
            float yc3 = -CCB * (x0 * sh5 + x1 * sh4 + x3 * sh8 + x4 * sh7)
                      - CCC * (x2 * sh7 + x3 * sh6);
            float yc4 = CCB * (x1 * sh5 - x3 * sh7) + CCA * (x2 * sh8 + x4 * sh6);
#pragma unroll
            for (int w = 0; w < 4; ++w) {
                float wa = wd[u * 4 + w];
                float wb = wd[20 + u * 4 + w];
                float wc = wd[40 + u * 4 + w];
                float we = wd[60 + u * 4 + w];
                od0[w] = fmaf(dot, wc, od0[w]);
                od1[w * 3 + 0] = fmaf(yb0, wb, od1[w * 3 + 0]);
                od1[w * 3 + 1] = fmaf(yb1, wb, od1[w * 3 + 1]);
                od1[w * 3 + 2] = fmaf(yb2, wb, od1[w * 3 + 2]);
                od2[w * 5 + 0] = fmaf(x0, wa, fmaf(yc0, we, od2[w * 5 + 0]));
                od2[w * 5 + 1] = fmaf(x1, wa, fmaf(yc1, we, od2[w * 5 + 1]));
                od2[w * 5 + 2] = fmaf(x2, wa, fmaf(yc2, we, od2[w * 5 + 2]));
                od2[w * 5 + 3] = fmaf(x3, wa, fmaf(yc3, we, od2[w * 5 + 3]));
                od2[w * 5 + 4] = fmaf(x4, wa, fmaf(yc4, we, od2[w * 5 + 4]));
            }
        }
#pragma unroll
        for (int w = 0; w < 4; ++w) atomAddF(o + 72 + w, od0[w]);
#pragma unroll
        for (int t = 0; t < 12; ++t) atomAddF(o + 76 + t, od1[t]);
#pragma unroll
        for (int t = 0; t < 20; ++t) atomAddF(o + 88 + t, od2[t]);
    }
}

extern "C" void kernel_launch(void* const* d_in, const int* in_sizes, int n_in,
                              void* d_out, int out_size, void* d_ws, size_t ws_size,
                              hipStream_t stream) {
    const float* f_in = (const float*)d_in[0];
    const int*   eidx = (const int*)d_in[1];
    const float* pos  = (const float*)d_in[2];
    const float* W1s = (const float*)d_in[5];
    const float* W2s = (const float*)d_in[6];
    const float* W1p = (const float*)d_in[7];
    const float* W2p = (const float*)d_in[8];
    const float* W1d = (const float*)d_in[9];
    const float* W2d = (const float*)d_in[10];

    const int E = in_sizes[1] / 2;
    const int N = in_sizes[0] / 162;
    const float snorm = (float)(1.0 / sqrt((double)E / (double)N));
    const float base = 0.05590169943749474f * snorm;   // sqrt2/(8*sqrt10) * snorm
    const int eBlocks = (E + 255) / 256;

    // ws: rows int[E] | cursor int[N] | rec float[56N] | table float[(NB+1)*TROW]
    const size_t rowsBytes = (size_t)E * sizeof(int);
    const size_t curOff = rowsBytes;
    const size_t recOff = (curOff + (size_t)N * sizeof(int) + 15) & ~((size_t)15);
    const size_t tabOff = (recOff + (size_t)N * RSTR * sizeof(float) + 15) & ~((size_t)15);

    // dynamic table size: prefer 2048 bins, degrade if workspace is tight
    int NB = 0;
    if (ws_size > tabOff) {
        size_t rows_avail = (ws_size - tabOff) / (TROW * sizeof(float));
        if (rows_avail >= 513) NB = (int)((rows_avail - 1) < 2048 ? (rows_avail - 1) : 2048);
    }

    if (NB >= 512) {
        int*   rows   = (int*)d_ws;
        int*   cursor = (int*)((char*)d_ws + curOff);
        float* rec    = (float*)((char*)d_ws + recOff);
        float* table  = (float*)((char*)d_ws + tabOff);
        const float Delta = 5.0f / (float)NB;
        const float invDelta = (float)NB / 5.0f;

        hipMemsetAsync(cursor, 0, (size_t)N * sizeof(int), stream);
        build_rec_count<<<eBlocks, 256, 0, stream>>>(f_in, pos, eidx, rec, cursor, N, E);
        build_table<<<NB + 1, 256, 0, stream>>>(W1s, W2s, W1p, W2p, W1d, W2d,
                                                table, Delta, base);
        scan_kernel<<<1, 1024, 0, stream>>>(cursor, N);
        permute_rows<<<eBlocks, 256, 0, stream>>>(eidx, cursor, rows, E);
        const int bRole = (4 * N + 255) / 256;
        gather_kernel<<<3 * bRole, 256, 0, stream>>>(
            rec, rows, cursor, table, (float*)d_out, N, NB, invDelta);
    } else {
        hipMemsetAsync(d_out, 0, (size_t)out_size * sizeof(float), stream);
        eqconv_edge_kernel_atomic<<<eBlocks, TPB, 0, stream>>>(
            f_in, eidx, pos, W1s, W2s, W1p, W2p, W1d, W2d,
            (float*)d_out, E, snorm);
    }
}